// Round 18
// baseline (373.746 us; speedup 1.0000x reference)
//
#include <hip/hip_runtime.h>

// ---------------------------------------------------------------------------
// HeteroSAGE: CSR pull; CSR built with ZERO per-edge global atomics.
//   prep -> partition3 (full machine) -> fill_proj (fill windows ∥ MFMA proj,
//   independent phases) -> pull_paper / pull_author (round-14 best) -> pull2.
// ---------------------------------------------------------------------------

typedef unsigned short ushort_t;
typedef __attribute__((ext_vector_type(8))) short bf16x8;
typedef __attribute__((ext_vector_type(4))) float f32x4;

#define PWBITS 9
#define PWIN   (1 << PWBITS)     // 512 dsts per window
#define PCHUNK 4096              // edges per partition block
#define CAPPAD 2048              // bucket slack
#define FW_R   12                // fill regs: 12 x uint4 = 12288 >= max cap

__device__ inline ushort_t f2bf(float f) {
    unsigned u = __float_as_uint(f);
    unsigned r = (u + 0x7FFFu + ((u >> 16) & 1u)) >> 16;
    return (ushort_t)r;
}
__device__ inline float bf2f_lo(unsigned u) { return __uint_as_float(u << 16); }
__device__ inline float bf2f_hi(unsigned u) { return __uint_as_float(u & 0xFFFF0000u); }
__device__ inline int ntl(const int* p) { return __builtin_nontemporal_load(p); }

__global__ void prep_weights(
    const float* __restrict__ Wl1_pp, const float* __restrict__ Wr1_pp,
    const float* __restrict__ Wl1_ap, const float* __restrict__ Wr1_ap,
    const float* __restrict__ Wl1_pa, const float* __restrict__ Wr1_pa,
    const float* __restrict__ bl1_pp, const float* __restrict__ bl1_ap,
    const float* __restrict__ bl1_pa,
    const float* __restrict__ Wl2_pp, const float* __restrict__ bl2_pp,
    const float* __restrict__ Wr2_pp,
    const float* __restrict__ Wl2_ap, const float* __restrict__ bl2_ap,
    const float* __restrict__ Wr2_ap,
    const float* __restrict__ W_lin, const float* __restrict__ b_lin,
    float* __restrict__ Wcomb_p, float* __restrict__ Wcomb_a,
    ushort_t* __restrict__ Wfrag_p, ushort_t* __restrict__ Wfrag_a,
    float* __restrict__ bias_p, float* __restrict__ bias_a,
    float* __restrict__ vv)
{
    int t = threadIdx.x;
    for (int idx = t; idx < 64 * 96; idx += 256) {
        int i = idx / 96, j = idx % 96;
        float v;
        if (j < 32)       v = Wl1_pp[i * 32 + j];
        else if (j < 64)  v = Wl1_pa[i * 32 + (j - 32)];
        else              v = Wr1_pp[i * 32 + (j - 64)] + Wr1_ap[i * 32 + (j - 64)];
        Wcomb_p[idx] = v;
    }
    for (int idx = t; idx < 64 * 64; idx += 256) {
        int i = idx / 64, j = idx % 64;
        Wcomb_a[idx] = (j < 32) ? Wl1_ap[i * 32 + j] : Wr1_pa[i * 32 + (j - 32)];
    }
    if (t < 32) {
        bias_p[t] = bl1_pp[t] + bl1_ap[t];
        bias_a[t] = bl1_pa[t];
        float vpp = 0.f, vr = 0.f, vap = 0.f;
        for (int j = 0; j < 32; ++j) {
            float wl = W_lin[j];
            vpp += Wl2_pp[t * 32 + j] * wl;
            vr  += (Wr2_pp[t * 32 + j] + Wr2_ap[t * 32 + j]) * wl;
            vap += Wl2_ap[t * 32 + j] * wl;
        }
        vv[t] = vpp; vv[32 + t] = vr; vv[96 + t] = vap;
    }
    if (t == 0) {
        float c = b_lin[0];
        for (int j = 0; j < 32; ++j) c += (bl2_pp[j] + bl2_ap[j]) * W_lin[j];
        vv[64] = c;
    }
    __syncthreads();
    for (int idx = t; idx < 12 * 64 * 8; idx += 256) {
        int f = idx >> 9, l = (idx >> 3) & 63, j = idx & 7;
        int nt = f >> 1, kh = f & 1;
        int k = kh * 32 + 8 * (l >> 4) + j;
        int n = nt * 16 + (l & 15);
        Wfrag_p[idx] = f2bf(Wcomb_p[k * 96 + n]);
    }
    for (int idx = t; idx < 8 * 64 * 8; idx += 256) {
        int f = idx >> 9, l = (idx >> 3) & 63, j = idx & 7;
        int nt = f >> 1, kh = f & 1;
        int k = kh * 32 + 8 * (l >> 4) + j;
        int n = nt * 16 + (l & 15);
        Wfrag_a[idx] = f2bf(Wcomb_a[k * 64 + n]);
    }
}

// one launch, all 3 relations. Register-staged edges (single stream read),
// LDS window counts, line-padded cursor claims.
__global__ __launch_bounds__(256)
void partition3(
    const int* __restrict__ src0, const int* __restrict__ dst0, int E0,
    unsigned* __restrict__ bk0, int cap0, int nw0, int* __restrict__ wc0,
    const int* __restrict__ src1, const int* __restrict__ dst1, int E1,
    unsigned* __restrict__ bk1, int cap1, int nw1, int* __restrict__ wc1,
    const int* __restrict__ src2, const int* __restrict__ dst2, int E2,
    unsigned* __restrict__ bk2, int cap2, int nw2, int* __restrict__ wc2)
{
    __shared__ int lcnt[PWIN];
    __shared__ int lbase[PWIN];
    int nb0 = (E0 + PCHUNK - 1) / PCHUNK;
    int nb1 = (E1 + PCHUNK - 1) / PCHUNK;
    int b = blockIdx.x;
    const int* src; const int* dst; int E; unsigned* bk; int cap; int nw; int* wc; int chunk;
    if (b < nb0)            { src = src0; dst = dst0; E = E0; bk = bk0; cap = cap0; nw = nw0; wc = wc0; chunk = b; }
    else if (b < nb0 + nb1) { src = src1; dst = dst1; E = E1; bk = bk1; cap = cap1; nw = nw1; wc = wc1; chunk = b - nb0; }
    else                    { src = src2; dst = dst2; E = E2; bk = bk2; cap = cap2; nw = nw2; wc = wc2; chunk = b - nb0 - nb1; }
    int e0 = chunk * PCHUNK;
    int d_[16], s_[16];
#pragma unroll
    for (int r = 0; r < 4; ++r) {
        int base = e0 + r * 1024 + threadIdx.x * 4;
        if (base + 3 < E) {
            int4 dv = *(const int4*)(dst + base);
            int4 sv = *(const int4*)(src + base);
            d_[r * 4 + 0] = dv.x; d_[r * 4 + 1] = dv.y; d_[r * 4 + 2] = dv.z; d_[r * 4 + 3] = dv.w;
            s_[r * 4 + 0] = sv.x; s_[r * 4 + 1] = sv.y; s_[r * 4 + 2] = sv.z; s_[r * 4 + 3] = sv.w;
        } else {
#pragma unroll
            for (int k = 0; k < 4; ++k) {
                int e = base + k;
                d_[r * 4 + k] = (e < E) ? dst[e] : -1;
                s_[r * 4 + k] = 0;
            }
        }
    }
    for (int i = threadIdx.x; i < nw; i += 256) lcnt[i] = 0;
    __syncthreads();
#pragma unroll
    for (int k = 0; k < 16; ++k)
        if (d_[k] >= 0) atomicAdd(&lcnt[((unsigned)d_[k]) >> PWBITS], 1);
    __syncthreads();
    for (int i = threadIdx.x; i < nw; i += 256) {
        int c = lcnt[i];
        lbase[i] = (c > 0) ? atomicAdd(&wc[i * 16], c) : 0;
        lcnt[i] = 0;
    }
    __syncthreads();
#pragma unroll
    for (int k = 0; k < 16; ++k) {
        int d = d_[k];
        if (d >= 0) {
            int w = ((unsigned)d) >> PWBITS;
            int off = lbase[w] + atomicAdd(&lcnt[w], 1);
            if (off < cap)
                bk[(size_t)w * cap + off] =
                    (((unsigned)(d & (PWIN - 1))) << 18) | (unsigned)s_[k];
        }
    }
}

// ---------------- fill body -------------------------------------------------
__device__ inline void fill_body(
    int b, const unsigned* __restrict__ bk, const int* __restrict__ wc, int cap,
    int* __restrict__ csr, int* __restrict__ cnt, int* __restrict__ rs,
    int N, int w, int* lc, int* wsum, int* wpre)
{
    int d0 = w << PWBITS;
    int sz = wc[w * 16]; if (sz > cap) sz = cap;
    const unsigned* bkt = bk + (size_t)w * cap;
    uint4 u[FW_R];
#pragma unroll
    for (int r = 0; r < FW_R; ++r) {
        int i4 = r * 1024 + threadIdx.x * 4;
        if (i4 + 3 < sz) {
            u[r] = *(const uint4*)(bkt + i4);
        } else {
            u[r].x = (i4 + 0 < sz) ? bkt[i4 + 0] : 0xFFFFFFFFu;
            u[r].y = (i4 + 1 < sz) ? bkt[i4 + 1] : 0xFFFFFFFFu;
            u[r].z = (i4 + 2 < sz) ? bkt[i4 + 2] : 0xFFFFFFFFu;
            u[r].w = (i4 + 3 < sz) ? bkt[i4 + 3] : 0xFFFFFFFFu;
        }
    }
    for (int i = threadIdx.x; i < PWIN; i += 256) lc[i] = 0;
    __syncthreads();
#pragma unroll
    for (int r = 0; r < FW_R; ++r) {
        if (u[r].x != 0xFFFFFFFFu) atomicAdd(&lc[u[r].x >> 18], 1);
        if (u[r].y != 0xFFFFFFFFu) atomicAdd(&lc[u[r].y >> 18], 1);
        if (u[r].z != 0xFFFFFFFFu) atomicAdd(&lc[u[r].z >> 18], 1);
        if (u[r].w != 0xFFFFFFFFu) atomicAdd(&lc[u[r].w >> 18], 1);
    }
    __syncthreads();
    {
        int i = threadIdx.x * 2;
        int d = d0 + i;
        if (d < N)     cnt[d] = lc[i];
        if (d + 1 < N) cnt[d + 1] = lc[i + 1];
    }
    int t2 = threadIdx.x * 2;
    int v0 = lc[t2], v1 = lc[t2 + 1];
    int ts = v0 + v1;
    int lane = threadIdx.x & 63;
    int wid = threadIdx.x >> 6;
    int incl = ts;
#pragma unroll
    for (int off = 1; off < 64; off <<= 1) {
        int o = __shfl_up(incl, off);
        if (lane >= off) incl += o;
    }
    if (lane == 63) wsum[wid] = incl;
    __syncthreads();
    if (threadIdx.x == 0) {
        int r = 0;
        for (int i = 0; i < 4; ++i) { wpre[i] = r; r += wsum[i]; }
    }
    __syncthreads();
    int run = w * cap + wpre[wid] + (incl - ts);
    lc[t2] = run;
    if (d0 + t2 < N) rs[d0 + t2] = run;
    run += v0;
    lc[t2 + 1] = run;
    if (d0 + t2 + 1 < N) rs[d0 + t2 + 1] = run;
    __syncthreads();
#pragma unroll
    for (int r = 0; r < FW_R; ++r) {
        if (u[r].x != 0xFFFFFFFFu) { int p = atomicAdd(&lc[u[r].x >> 18], 1); csr[p] = (int)(u[r].x & 0x3FFFFu); }
        if (u[r].y != 0xFFFFFFFFu) { int p = atomicAdd(&lc[u[r].y >> 18], 1); csr[p] = (int)(u[r].y & 0x3FFFFu); }
        if (u[r].z != 0xFFFFFFFFu) { int p = atomicAdd(&lc[u[r].z >> 18], 1); csr[p] = (int)(u[r].z & 0x3FFFFu); }
        if (u[r].w != 0xFFFFFFFFu) { int p = atomicAdd(&lc[u[r].w >> 18], 1); csr[p] = (int)(u[r].w & 0x3FFFFu); }
    }
}

// ---------------- proj bodies ----------------------------------------------
__device__ inline bf16x8 cvt8(const float* p) {
    float4 a = *(const float4*)p;
    float4 b = *(const float4*)(p + 4);
    bf16x8 r;
    r[0] = (short)f2bf(a.x); r[1] = (short)f2bf(a.y);
    r[2] = (short)f2bf(a.z); r[3] = (short)f2bf(a.w);
    r[4] = (short)f2bf(b.x); r[5] = (short)f2bf(b.y);
    r[6] = (short)f2bf(b.z); r[7] = (short)f2bf(b.w);
    return r;
}

__device__ inline void proj_paper_body(
    int blk, const float* __restrict__ x, const ushort_t* __restrict__ Wfrag,
    const float* __restrict__ bias,
    ushort_t* __restrict__ h_pp, ushort_t* __restrict__ h_pa,
    float* __restrict__ root_p, int N)
{
    int wave = threadIdx.x >> 6, lane = threadIdx.x & 63;
    int mbase = blk * 64 + wave * 16;
    int row = lane & 15, grp = lane >> 4;
    int nA = mbase + row; if (nA > N - 1) nA = N - 1;
    const float* xr = x + (size_t)nA * 64 + grp * 8;
    bf16x8 a0 = cvt8(xr);
    bf16x8 a1 = cvt8(xr + 32);
    f32x4 acc0 = {0.f, 0.f, 0.f, 0.f}, acc1 = acc0, acc2 = acc0, acc3 = acc0;
    float bp0 = bias[row];
    float bp1 = bias[16 + row];
    f32x4 acc4 = {bp0, bp0, bp0, bp0};
    f32x4 acc5 = {bp1, bp1, bp1, bp1};
    const bf16x8* wf = (const bf16x8*)(Wfrag) + lane;
    acc0 = __builtin_amdgcn_mfma_f32_16x16x32_bf16(a0, wf[0 * 64], acc0, 0, 0, 0);
    acc0 = __builtin_amdgcn_mfma_f32_16x16x32_bf16(a1, wf[1 * 64], acc0, 0, 0, 0);
    acc1 = __builtin_amdgcn_mfma_f32_16x16x32_bf16(a0, wf[2 * 64], acc1, 0, 0, 0);
    acc1 = __builtin_amdgcn_mfma_f32_16x16x32_bf16(a1, wf[3 * 64], acc1, 0, 0, 0);
    acc2 = __builtin_amdgcn_mfma_f32_16x16x32_bf16(a0, wf[4 * 64], acc2, 0, 0, 0);
    acc2 = __builtin_amdgcn_mfma_f32_16x16x32_bf16(a1, wf[5 * 64], acc2, 0, 0, 0);
    acc3 = __builtin_amdgcn_mfma_f32_16x16x32_bf16(a0, wf[6 * 64], acc3, 0, 0, 0);
    acc3 = __builtin_amdgcn_mfma_f32_16x16x32_bf16(a1, wf[7 * 64], acc3, 0, 0, 0);
    acc4 = __builtin_amdgcn_mfma_f32_16x16x32_bf16(a0, wf[8 * 64], acc4, 0, 0, 0);
    acc4 = __builtin_amdgcn_mfma_f32_16x16x32_bf16(a1, wf[9 * 64], acc4, 0, 0, 0);
    acc5 = __builtin_amdgcn_mfma_f32_16x16x32_bf16(a0, wf[10 * 64], acc5, 0, 0, 0);
    acc5 = __builtin_amdgcn_mfma_f32_16x16x32_bf16(a1, wf[11 * 64], acc5, 0, 0, 0);
    int node0 = mbase + grp * 4;
#pragma unroll
    for (int reg = 0; reg < 4; ++reg) {
        int nd = node0 + reg;
        if (nd < N) {
            size_t b32 = (size_t)nd * 32;
            h_pp[b32 + row]        = f2bf(acc0[reg]);
            h_pp[b32 + 16 + row]   = f2bf(acc1[reg]);
            h_pa[b32 + row]        = f2bf(acc2[reg]);
            h_pa[b32 + 16 + row]   = f2bf(acc3[reg]);
            root_p[b32 + row]      = acc4[reg];
            root_p[b32 + 16 + row] = acc5[reg];
        }
    }
}

__device__ inline void proj_author_body(
    int blk, const float* __restrict__ x, const ushort_t* __restrict__ Wfrag,
    const float* __restrict__ bias,
    ushort_t* __restrict__ h_ap, float* __restrict__ root_a, int N)
{
    int wave = threadIdx.x >> 6, lane = threadIdx.x & 63;
    int mbase = blk * 64 + wave * 16;
    int row = lane & 15, grp = lane >> 4;
    int nA = mbase + row; if (nA > N - 1) nA = N - 1;
    const float* xr = x + (size_t)nA * 64 + grp * 8;
    bf16x8 a0 = cvt8(xr);
    bf16x8 a1 = cvt8(xr + 32);
    f32x4 acc0 = {0.f, 0.f, 0.f, 0.f}, acc1 = acc0;
    float bp0 = bias[row];
    float bp1 = bias[16 + row];
    f32x4 acc2 = {bp0, bp0, bp0, bp0};
    f32x4 acc3 = {bp1, bp1, bp1, bp1};
    const bf16x8* wf = (const bf16x8*)(Wfrag) + lane;
    acc0 = __builtin_amdgcn_mfma_f32_16x16x32_bf16(a0, wf[0 * 64], acc0, 0, 0, 0);
    acc0 = __builtin_amdgcn_mfma_f32_16x16x32_bf16(a1, wf[1 * 64], acc0, 0, 0, 0);
    acc1 = __builtin_amdgcn_mfma_f32_16x16x32_bf16(a0, wf[2 * 64], acc1, 0, 0, 0);
    acc1 = __builtin_amdgcn_mfma_f32_16x16x32_bf16(a1, wf[3 * 64], acc1, 0, 0, 0);
    acc2 = __builtin_amdgcn_mfma_f32_16x16x32_bf16(a0, wf[4 * 64], acc2, 0, 0, 0);
    acc2 = __builtin_amdgcn_mfma_f32_16x16x32_bf16(a1, wf[5 * 64], acc2, 0, 0, 0);
    acc3 = __builtin_amdgcn_mfma_f32_16x16x32_bf16(a0, wf[6 * 64], acc3, 0, 0, 0);
    acc3 = __builtin_amdgcn_mfma_f32_16x16x32_bf16(a1, wf[7 * 64], acc3, 0, 0, 0);
    int node0 = mbase + grp * 4;
#pragma unroll
    for (int reg = 0; reg < 4; ++reg) {
        int nd = node0 + reg;
        if (nd < N) {
            size_t b32 = (size_t)nd * 32;
            h_ap[b32 + row]        = f2bf(acc0[reg]);
            h_ap[b32 + 16 + row]   = f2bf(acc1[reg]);
            root_a[b32 + row]      = acc2[reg];
            root_a[b32 + 16 + row] = acc3[reg];
        }
    }
}

// fused: fill windows [0, nwt), paper-proj [nwt, nwt+pbp), author after.
// fill and proj touch disjoint data (buckets/csr vs x/h/root) and both
// depend only on partition3 / nothing respectively.
__global__ __launch_bounds__(256)
void fill_proj(
    const unsigned* __restrict__ bk0, const int* __restrict__ wc0, int cap0,
    int* __restrict__ csr0, int* __restrict__ cnt0, int* __restrict__ rs0, int N0, int nw0,
    const unsigned* __restrict__ bk1, const int* __restrict__ wc1, int cap1,
    int* __restrict__ csr1, int* __restrict__ cnt1, int* __restrict__ rs1, int N1, int nw1,
    const unsigned* __restrict__ bk2, const int* __restrict__ wc2, int cap2,
    int* __restrict__ csr2, int* __restrict__ cnt2, int* __restrict__ rs2, int N2, int nw2,
    const float* __restrict__ xp, const float* __restrict__ xa,
    const ushort_t* __restrict__ Wfp, const ushort_t* __restrict__ Wfa,
    const float* __restrict__ bias_p, const float* __restrict__ bias_a,
    ushort_t* __restrict__ h_pp, ushort_t* __restrict__ h_pa,
    ushort_t* __restrict__ h_ap,
    float* __restrict__ root_p, float* __restrict__ root_a,
    int NP, int NA, int pbp)
{
    __shared__ int lc[PWIN];
    __shared__ int wsum[4], wpre[4];
    int b = blockIdx.x;
    int nwt = nw0 + nw1 + nw2;
    if (b < nwt) {
        const unsigned* bk; const int* wc; int cap; int* csr; int* cnt; int* rs; int N; int w;
        if (b < nw0)            { bk = bk0; wc = wc0; cap = cap0; csr = csr0; cnt = cnt0; rs = rs0; N = N0; w = b; }
        else if (b < nw0 + nw1) { bk = bk1; wc = wc1; cap = cap1; csr = csr1; cnt = cnt1; rs = rs1; N = N1; w = b - nw0; }
        else                    { bk = bk2; wc = wc2; cap = cap2; csr = csr2; cnt = cnt2; rs = rs2; N = N2; w = b - nw0 - nw1; }
        fill_body(b, bk, wc, cap, csr, cnt, rs, N, w, lc, wsum, wpre);
    } else if (b < nwt + pbp) {
        proj_paper_body(b - nwt, xp, Wfp, bias_p, h_pp, h_pa, root_p, NP);
    } else {
        proj_author_body(b - nwt - pbp, xa, Wfa, bias_a, h_ap, root_a, NA);
    }
}

#define ACC8(A, U) \
    A[0] += bf2f_lo((U).x); A[1] += bf2f_hi((U).x); \
    A[2] += bf2f_lo((U).y); A[3] += bf2f_hi((U).y); \
    A[4] += bf2f_lo((U).z); A[5] += bf2f_hi((U).z); \
    A[6] += bf2f_lo((U).w); A[7] += bf2f_hi((U).w);

__global__ __launch_bounds__(256, 8)
void pull_paper(const ushort_t* __restrict__ h_pp, const ushort_t* __restrict__ h_ap,
                const float* __restrict__ root,
                const int* __restrict__ csr_pp, const int* __restrict__ rs_pp,
                const int* __restrict__ cnt_pp,
                const int* __restrict__ csr_ap, const int* __restrict__ rs_ap,
                const int* __restrict__ cnt_ap,
                const float* __restrict__ vv,
                float* __restrict__ s_pp, float* __restrict__ out, int N)
{
    __shared__ float v0[32], v1[32];
    __shared__ float c2s;
    if (threadIdx.x < 32) { v0[threadIdx.x] = vv[threadIdx.x]; v1[threadIdx.x] = vv[32 + threadIdx.x]; }
    if (threadIdx.x == 0) c2s = vv[64];
    __syncthreads();
    int n = blockIdx.x * 64 + (threadIdx.x >> 2);
    if (n >= N) return;
    int c = threadIdx.x & 3;
    float a[8];
#pragma unroll
    for (int k = 0; k < 8; ++k) a[k] = 0.f;
    int s1 = rs_pp[n], k1 = cnt_pp[n], e1 = s1 + k1;
    int j = s1;
    for (; j + 4 <= e1; j += 4) {
        int i0 = ntl(csr_pp + j), i1 = ntl(csr_pp + j + 1);
        int i2 = ntl(csr_pp + j + 2), i3 = ntl(csr_pp + j + 3);
        uint4 u0 = ((const uint4*)(h_pp + (size_t)i0 * 32))[c];
        uint4 u1 = ((const uint4*)(h_pp + (size_t)i1 * 32))[c];
        uint4 u2 = ((const uint4*)(h_pp + (size_t)i2 * 32))[c];
        uint4 u3 = ((const uint4*)(h_pp + (size_t)i3 * 32))[c];
        ACC8(a, u0) ACC8(a, u1) ACC8(a, u2) ACC8(a, u3)
    }
    for (; j < e1; ++j) {
        uint4 u0 = ((const uint4*)(h_pp + (size_t)ntl(csr_pp + j) * 32))[c];
        ACC8(a, u0)
    }
    float b[8];
#pragma unroll
    for (int k = 0; k < 8; ++k) b[k] = 0.f;
    int s2 = rs_ap[n], k2 = cnt_ap[n], e2 = s2 + k2;
    j = s2;
    for (; j + 4 <= e2; j += 4) {
        int i0 = ntl(csr_ap + j), i1 = ntl(csr_ap + j + 1);
        int i2 = ntl(csr_ap + j + 2), i3 = ntl(csr_ap + j + 3);
        uint4 u0 = ((const uint4*)(h_ap + (size_t)i0 * 32))[c];
        uint4 u1 = ((const uint4*)(h_ap + (size_t)i1 * 32))[c];
        uint4 u2 = ((const uint4*)(h_ap + (size_t)i2 * 32))[c];
        uint4 u3 = ((const uint4*)(h_ap + (size_t)i3 * 32))[c];
        ACC8(b, u0) ACC8(b, u1) ACC8(b, u2) ACC8(b, u3)
    }
    for (; j < e2; ++j) {
        uint4 u0 = ((const uint4*)(h_ap + (size_t)ntl(csr_ap + j) * 32))[c];
        ACC8(b, u0)
    }
    float ipp = 1.0f / fmaxf((float)k1, 1.0f);
    float iap = 1.0f / fmaxf((float)k2, 1.0f);
    const float* rt = root + (size_t)n * 32 + 8 * c;
    float d0 = 0.f, d1 = 0.f;
#pragma unroll
    for (int k = 0; k < 8; ++k) {
        float p = fmaxf(rt[k] + a[k] * ipp + b[k] * iap, 0.f);
        d0 += p * v0[8 * c + k];
        d1 += p * v1[8 * c + k];
    }
    d0 += __shfl_xor(d0, 1); d0 += __shfl_xor(d0, 2);
    d1 += __shfl_xor(d1, 1); d1 += __shfl_xor(d1, 2);
    if (c == 0) { s_pp[n] = d0; out[n] = d1 + c2s; }
}

__global__ __launch_bounds__(256, 8)
void pull_author(const ushort_t* __restrict__ h_pa, const float* __restrict__ root,
                 const int* __restrict__ csr_pa, const int* __restrict__ rs_pa,
                 const int* __restrict__ cnt_pa,
                 const float* __restrict__ vv, float* __restrict__ s_ap, int N)
{
    __shared__ float v0[32];
    if (threadIdx.x < 32) v0[threadIdx.x] = vv[96 + threadIdx.x];
    __syncthreads();
    int n = blockIdx.x * 64 + (threadIdx.x >> 2);
    if (n >= N) return;
    int c = threadIdx.x & 3;
    float a[8];
#pragma unroll
    for (int k = 0; k < 8; ++k) a[k] = 0.f;
    int s1 = rs_pa[n], k1 = cnt_pa[n], e1 = s1 + k1;
    int j = s1;
    for (; j + 4 <= e1; j += 4) {
        int i0 = ntl(csr_pa + j), i1 = ntl(csr_pa + j + 1);
        int i2 = ntl(csr_pa + j + 2), i3 = ntl(csr_pa + j + 3);
        uint4 u0 = ((const uint4*)(h_pa + (size_t)i0 * 32))[c];
        uint4 u1 = ((const uint4*)(h_pa + (size_t)i1 * 32))[c];
        uint4 u2 = ((const uint4*)(h_pa + (size_t)i2 * 32))[c];
        uint4 u3 = ((const uint4*)(h_pa + (size_t)i3 * 32))[c];
        ACC8(a, u0) ACC8(a, u1) ACC8(a, u2) ACC8(a, u3)
    }
    for (; j < e1; ++j) {
        uint4 u0 = ((const uint4*)(h_pa + (size_t)ntl(csr_pa + j) * 32))[c];
        ACC8(a, u0)
    }
    float ip = 1.0f / fmaxf((float)k1, 1.0f);
    const float* rt = root + (size_t)n * 32 + 8 * c;
    float d0 = 0.f;
#pragma unroll
    for (int k = 0; k < 8; ++k) {
        float p = fmaxf(rt[k] + a[k] * ip, 0.f);
        d0 += p * v0[8 * c + k];
    }
    d0 += __shfl_xor(d0, 1); d0 += __shfl_xor(d0, 2);
    if (c == 0) s_ap[n] = d0;
}

__global__ __launch_bounds__(256, 8)
void pull2(const float* __restrict__ s_pp, const float* __restrict__ s_ap,
           const int* __restrict__ csr_pp, const int* __restrict__ rs_pp,
           const int* __restrict__ cnt_pp,
           const int* __restrict__ csr_ap, const int* __restrict__ rs_ap,
           const int* __restrict__ cnt_ap,
           float* __restrict__ out, int N)
{
    int g = (blockIdx.x * blockDim.x + threadIdx.x) >> 2;
    int c = threadIdx.x & 3;
    if (g >= N) return;
    int s1 = rs_pp[g], k1 = cnt_pp[g], e1 = s1 + k1;
    float t = 0.f;
    for (int j = s1 + c; j < e1; j += 4) t += s_pp[ntl(csr_pp + j)];
    int s2 = rs_ap[g], k2 = cnt_ap[g], e2 = s2 + k2;
    float u = 0.f;
    for (int j = s2 + c; j < e2; j += 4) u += s_ap[ntl(csr_ap + j)];
    t += __shfl_xor(t, 1); t += __shfl_xor(t, 2);
    u += __shfl_xor(u, 1); u += __shfl_xor(u, 2);
    if (c == 0) {
        out[g] += t / fmaxf((float)k1, 1.f) + u / fmaxf((float)k2, 1.f);
    }
}

extern "C" void kernel_launch(void* const* d_in, const int* in_sizes, int n_in,
                              void* d_out, int out_size, void* d_ws, size_t ws_size,
                              hipStream_t stream)
{
    const float* x_paper  = (const float*)d_in[0];
    const float* x_author = (const float*)d_in[1];
    const int* src_pp = (const int*)d_in[2];
    const int* dst_pp = (const int*)d_in[3];
    const int* src_ap = (const int*)d_in[4];
    const int* dst_ap = (const int*)d_in[5];
    const int* src_pa = (const int*)d_in[6];
    const int* dst_pa = (const int*)d_in[7];
    const float* Wl1_pp = (const float*)d_in[8];
    const float* bl1_pp = (const float*)d_in[9];
    const float* Wr1_pp = (const float*)d_in[10];
    const float* Wl1_ap = (const float*)d_in[11];
    const float* bl1_ap = (const float*)d_in[12];
    const float* Wr1_ap = (const float*)d_in[13];
    const float* Wl1_pa = (const float*)d_in[14];
    const float* bl1_pa = (const float*)d_in[15];
    const float* Wr1_pa = (const float*)d_in[16];
    const float* Wl2_pp = (const float*)d_in[17];
    const float* bl2_pp = (const float*)d_in[18];
    const float* Wr2_pp = (const float*)d_in[19];
    const float* Wl2_ap = (const float*)d_in[20];
    const float* bl2_ap = (const float*)d_in[21];
    const float* Wr2_ap = (const float*)d_in[22];
    const float* W_lin  = (const float*)d_in[23];
    const float* b_lin  = (const float*)d_in[24];

    const int NP = in_sizes[0] / 64;
    const int NA = in_sizes[1] / 64;
    const int E_PP = in_sizes[2];
    const int E_AP = in_sizes[4];
    const int E_PA = in_sizes[6];

    const int nw_pp = (NP + PWIN - 1) >> PWBITS;
    const int nw_ap = nw_pp;
    const int nw_pa = (NA + PWIN - 1) >> PWBITS;
    const int cap_pp = ((E_PP / nw_pp + CAPPAD) + 3) & ~3;
    const int cap_ap = ((E_AP / nw_ap + CAPPAD) + 3) & ~3;
    const int cap_pa = ((E_PA / nw_pa + CAPPAD) + 3) & ~3;

    // ---- workspace ----
    char* wp = (char*)d_ws;
    int* wcur = (int*)wp;             wp += (size_t)3 * PWIN * 16 * 4;
    unsigned* bk_pp = (unsigned*)wp;  wp += (size_t)nw_pp * cap_pp * 4;
    unsigned* bk_ap = (unsigned*)wp;  wp += (size_t)nw_ap * cap_ap * 4;
    unsigned* bk_pa = (unsigned*)wp;  wp += (size_t)nw_pa * cap_pa * 4;
    int* csr_pp = (int*)wp;           wp += (size_t)nw_pp * cap_pp * 4;
    int* csr_ap = (int*)wp;           wp += (size_t)nw_ap * cap_ap * 4;
    int* csr_pa = (int*)wp;           wp += (size_t)nw_pa * cap_pa * 4;
    int* cnt    = (int*)wp;           wp += (size_t)(2 * NP + NA) * 4;
    int* rs     = (int*)wp;           wp += (size_t)(2 * NP + NA) * 4;
    ushort_t* h_pp = (ushort_t*)wp;   wp += (size_t)NP * 32 * 2;
    ushort_t* h_pa = (ushort_t*)wp;   wp += (size_t)NP * 32 * 2;
    ushort_t* h_ap = (ushort_t*)wp;   wp += (size_t)NA * 32 * 2;
    float* root_a = (float*)wp;       wp += (size_t)NA * 32 * 4;
    float* s_pp   = (float*)wp;       wp += (size_t)NP * 4;
    float* s_ap   = (float*)wp;       wp += (size_t)NA * 4;
    float* Wcomb_p = (float*)wp;      wp += 64 * 96 * 4;
    float* Wcomb_a = (float*)wp;      wp += 64 * 64 * 4;
    ushort_t* Wfrag_p = (ushort_t*)wp; wp += 12 * 64 * 8 * 2;
    ushort_t* Wfrag_a = (ushort_t*)wp; wp += 8 * 64 * 8 * 2;
    float* bias_p = (float*)wp;       wp += 32 * 4;
    float* bias_a = (float*)wp;       wp += 32 * 4;
    float* vv     = (float*)wp;       wp += 128 * 4;
    // dedicated root_p if it fits; else overlay dead buckets (serial-safe
    // because fill_proj runs proj in the same dispatch as fill -> need fit)
    size_t used = (size_t)(wp - (char*)d_ws);
    size_t rootp_bytes = (size_t)NP * 32 * 4;
    bool roomy = (used + rootp_bytes) <= ws_size;
    float* root_p = roomy ? (float*)wp : (float*)bk_pp;

    int* cnt_pp = cnt,  * cnt_ap = cnt + NP,  * cnt_pa = cnt + 2 * NP;
    int* rs_pp  = rs,   * rs_ap  = rs + NP,   * rs_pa  = rs + 2 * NP;

    float* out = (float*)d_out;

    hipMemsetAsync(wcur, 0, (size_t)3 * PWIN * 16 * 4, stream);

    prep_weights<<<1, 256, 0, stream>>>(
        Wl1_pp, Wr1_pp, Wl1_ap, Wr1_ap, Wl1_pa, Wr1_pa,
        bl1_pp, bl1_ap, bl1_pa,
        Wl2_pp, bl2_pp, Wr2_pp, Wl2_ap, bl2_ap, Wr2_ap,
        W_lin, b_lin, Wcomb_p, Wcomb_a, Wfrag_p, Wfrag_a, bias_p, bias_a, vv);

    int nb_total = (E_PP + PCHUNK - 1) / PCHUNK + (E_AP + PCHUNK - 1) / PCHUNK
                 + (E_PA + PCHUNK - 1) / PCHUNK;
    int pbp = (NP + 63) / 64;
    int pba = (NA + 63) / 64;
    int nwt = nw_pp + nw_ap + nw_pa;

    partition3<<<nb_total, 256, 0, stream>>>(
        src_pp, dst_pp, E_PP, bk_pp, cap_pp, nw_pp, wcur + 0,
        src_ap, dst_ap, E_AP, bk_ap, cap_ap, nw_ap, wcur + PWIN * 16,
        src_pa, dst_pa, E_PA, bk_pa, cap_pa, nw_pa, wcur + 2 * PWIN * 16);

    if (roomy) {
        // fill ∥ proj in one dispatch (independent data)
        fill_proj<<<nwt + pbp + pba, 256, 0, stream>>>(
            bk_pp, wcur + 0,             cap_pp, csr_pp, cnt_pp, rs_pp, NP, nw_pp,
            bk_ap, wcur + PWIN * 16,     cap_ap, csr_ap, cnt_ap, rs_ap, NP, nw_ap,
            bk_pa, wcur + 2 * PWIN * 16, cap_pa, csr_pa, cnt_pa, rs_pa, NA, nw_pa,
            x_paper, x_author, Wfrag_p, Wfrag_a, bias_p, bias_a,
            h_pp, h_pa, h_ap, root_p, root_a, NP, NA, pbp);
    } else {
        // serial fallback: fill first (buckets die), then proj overlaying them
        fill_proj<<<nwt, 256, 0, stream>>>(
            bk_pp, wcur + 0,             cap_pp, csr_pp, cnt_pp, rs_pp, NP, nw_pp,
            bk_ap, wcur + PWIN * 16,     cap_ap, csr_ap, cnt_ap, rs_ap, NP, nw_ap,
            bk_pa, wcur + 2 * PWIN * 16, cap_pa, csr_pa, cnt_pa, rs_pa, NA, nw_pa,
            x_paper, x_author, Wfrag_p, Wfrag_a, bias_p, bias_a,
            h_pp, h_pa, h_ap, root_p, root_a, NP, NA, 0x40000000);
        fill_proj<<<pbp + pba, 256, 0, stream>>>(
            bk_pp, wcur + 0,             cap_pp, csr_pp, cnt_pp, rs_pp, NP, 0,
            bk_ap, wcur + PWIN * 16,     cap_ap, csr_ap, cnt_ap, rs_ap, NP, 0,
            bk_pa, wcur + 2 * PWIN * 16, cap_pa, csr_pa, cnt_pa, rs_pa, NA, 0,
            x_paper, x_author, Wfrag_p, Wfrag_a, bias_p, bias_a,
            h_pp, h_pa, h_ap, root_p, root_a, NP, NA, pbp);
    }

    pull_paper<<<(NP + 63) / 64, 256, 0, stream>>>(
        h_pp, h_ap, root_p, csr_pp, rs_pp, cnt_pp, csr_ap, rs_ap, cnt_ap,
        vv, s_pp, out, NP);
    pull_author<<<(NA + 63) / 64, 256, 0, stream>>>(
        h_pa, root_a, csr_pa, rs_pa, cnt_pa, vv, s_ap, NA);

    pull2<<<((size_t)NP * 4 + 255) / 256, 256, 0, stream>>>(
        s_pp, s_ap, csr_pp, rs_pp, cnt_pp, csr_ap, rs_ap, cnt_ap, out, NP);
}

// Round 19
// 346.128 us; speedup vs baseline: 1.0798x; 1.0798x over previous
//
#include <hip/hip_runtime.h>

// ---------------------------------------------------------------------------
// HeteroSAGE: CSR pull; CSR built with ZERO per-edge global atomics.
//   prep -> partition3 (LDS-staged, window-sorted COALESCED bucket writes) ->
//   fill_proj (fill windows ∥ MFMA proj) -> pull_pa (paper ∥ author pulls,
//   round-14 bodies) -> pull2.
// ---------------------------------------------------------------------------

typedef unsigned short ushort_t;
typedef __attribute__((ext_vector_type(8))) short bf16x8;
typedef __attribute__((ext_vector_type(4))) float f32x4;

#define PWBITS 9
#define PWIN   (1 << PWBITS)     // 512 dsts per window
#define PCHUNK 4096              // edges per partition block
#define CAPPAD 2048              // bucket slack
#define FW_R   12                // fill regs: 12 x uint4 = 12288 >= max cap

__device__ inline ushort_t f2bf(float f) {
    unsigned u = __float_as_uint(f);
    unsigned r = (u + 0x7FFFu + ((u >> 16) & 1u)) >> 16;
    return (ushort_t)r;
}
__device__ inline float bf2f_lo(unsigned u) { return __uint_as_float(u << 16); }
__device__ inline float bf2f_hi(unsigned u) { return __uint_as_float(u & 0xFFFF0000u); }
__device__ inline int ntl(const int* p) { return __builtin_nontemporal_load(p); }

__global__ void prep_weights(
    const float* __restrict__ Wl1_pp, const float* __restrict__ Wr1_pp,
    const float* __restrict__ Wl1_ap, const float* __restrict__ Wr1_ap,
    const float* __restrict__ Wl1_pa, const float* __restrict__ Wr1_pa,
    const float* __restrict__ bl1_pp, const float* __restrict__ bl1_ap,
    const float* __restrict__ bl1_pa,
    const float* __restrict__ Wl2_pp, const float* __restrict__ bl2_pp,
    const float* __restrict__ Wr2_pp,
    const float* __restrict__ Wl2_ap, const float* __restrict__ bl2_ap,
    const float* __restrict__ Wr2_ap,
    const float* __restrict__ W_lin, const float* __restrict__ b_lin,
    float* __restrict__ Wcomb_p, float* __restrict__ Wcomb_a,
    ushort_t* __restrict__ Wfrag_p, ushort_t* __restrict__ Wfrag_a,
    float* __restrict__ bias_p, float* __restrict__ bias_a,
    float* __restrict__ vv)
{
    int t = threadIdx.x;
    for (int idx = t; idx < 64 * 96; idx += 256) {
        int i = idx / 96, j = idx % 96;
        float v;
        if (j < 32)       v = Wl1_pp[i * 32 + j];
        else if (j < 64)  v = Wl1_pa[i * 32 + (j - 32)];
        else              v = Wr1_pp[i * 32 + (j - 64)] + Wr1_ap[i * 32 + (j - 64)];
        Wcomb_p[idx] = v;
    }
    for (int idx = t; idx < 64 * 64; idx += 256) {
        int i = idx / 64, j = idx % 64;
        Wcomb_a[idx] = (j < 32) ? Wl1_ap[i * 32 + j] : Wr1_pa[i * 32 + (j - 32)];
    }
    if (t < 32) {
        bias_p[t] = bl1_pp[t] + bl1_ap[t];
        bias_a[t] = bl1_pa[t];
        float vpp = 0.f, vr = 0.f, vap = 0.f;
        for (int j = 0; j < 32; ++j) {
            float wl = W_lin[j];
            vpp += Wl2_pp[t * 32 + j] * wl;
            vr  += (Wr2_pp[t * 32 + j] + Wr2_ap[t * 32 + j]) * wl;
            vap += Wl2_ap[t * 32 + j] * wl;
        }
        vv[t] = vpp; vv[32 + t] = vr; vv[96 + t] = vap;
    }
    if (t == 0) {
        float c = b_lin[0];
        for (int j = 0; j < 32; ++j) c += (bl2_pp[j] + bl2_ap[j]) * W_lin[j];
        vv[64] = c;
    }
    __syncthreads();
    for (int idx = t; idx < 12 * 64 * 8; idx += 256) {
        int f = idx >> 9, l = (idx >> 3) & 63, j = idx & 7;
        int nt = f >> 1, kh = f & 1;
        int k = kh * 32 + 8 * (l >> 4) + j;
        int n = nt * 16 + (l & 15);
        Wfrag_p[idx] = f2bf(Wcomb_p[k * 96 + n]);
    }
    for (int idx = t; idx < 8 * 64 * 8; idx += 256) {
        int f = idx >> 9, l = (idx >> 3) & 63, j = idx & 7;
        int nt = f >> 1, kh = f & 1;
        int k = kh * 32 + 8 * (l >> 4) + j;
        int n = nt * 16 + (l & 15);
        Wfrag_a[idx] = f2bf(Wcomb_a[k * 64 + n]);
    }
}

// one launch, all 3 relations. Register-staged edges (single stream read),
// LDS window counts + scan, then LDS window-SORTED staging so the global
// bucket writes are coalesced runs (kills the 4B-scatter write amplification).
__global__ __launch_bounds__(256)
void partition3(
    const int* __restrict__ src0, const int* __restrict__ dst0, int E0,
    unsigned* __restrict__ bk0, int cap0, int nw0, int* __restrict__ wc0,
    const int* __restrict__ src1, const int* __restrict__ dst1, int E1,
    unsigned* __restrict__ bk1, int cap1, int nw1, int* __restrict__ wc1,
    const int* __restrict__ src2, const int* __restrict__ dst2, int E2,
    unsigned* __restrict__ bk2, int cap2, int nw2, int* __restrict__ wc2)
{
    __shared__ int lcnt[PWIN];       // counts -> cursors
    __shared__ int lsta[PWIN];       // local exclusive starts
    __shared__ int lbase[PWIN];      // claimed global bases
    __shared__ unsigned stg[PCHUNK]; // window-sorted packed edges
    __shared__ ushort_t wsl[PCHUNK]; // per-slot window id
    __shared__ int wsum[4], wpre[4];
    int nb0 = (E0 + PCHUNK - 1) / PCHUNK;
    int nb1 = (E1 + PCHUNK - 1) / PCHUNK;
    int b = blockIdx.x;
    const int* src; const int* dst; int E; unsigned* bk; int cap; int* wc; int chunk;
    if (b < nb0)            { src = src0; dst = dst0; E = E0; bk = bk0; cap = cap0; wc = wc0; chunk = b; }
    else if (b < nb0 + nb1) { src = src1; dst = dst1; E = E1; bk = bk1; cap = cap1; wc = wc1; chunk = b - nb0; }
    else                    { src = src2; dst = dst2; E = E2; bk = bk2; cap = cap2; wc = wc2; chunk = b - nb0 - nb1; }
    int e0 = chunk * PCHUNK;
    int d_[16], s_[16];
#pragma unroll
    for (int r = 0; r < 4; ++r) {
        int base = e0 + r * 1024 + threadIdx.x * 4;
        if (base + 3 < E) {
            int4 dv = *(const int4*)(dst + base);
            int4 sv = *(const int4*)(src + base);
            d_[r * 4 + 0] = dv.x; d_[r * 4 + 1] = dv.y; d_[r * 4 + 2] = dv.z; d_[r * 4 + 3] = dv.w;
            s_[r * 4 + 0] = sv.x; s_[r * 4 + 1] = sv.y; s_[r * 4 + 2] = sv.z; s_[r * 4 + 3] = sv.w;
        } else {
#pragma unroll
            for (int k = 0; k < 4; ++k) {
                int e = base + k;
                d_[r * 4 + k] = (e < E) ? dst[e] : -1;
                s_[r * 4 + k] = 0;
            }
        }
    }
    for (int i = threadIdx.x; i < PWIN; i += 256) lcnt[i] = 0;
    __syncthreads();
#pragma unroll
    for (int k = 0; k < 16; ++k)
        if (d_[k] >= 0) atomicAdd(&lcnt[((unsigned)d_[k]) >> PWBITS], 1);
    __syncthreads();
    // claim global bases + exclusive scan (2 counters/thread over 512)
    int t2 = threadIdx.x * 2;
    int v0 = lcnt[t2], v1 = lcnt[t2 + 1];
    lbase[t2]     = (v0 > 0) ? atomicAdd(&wc[t2 * 16], v0) : 0;
    lbase[t2 + 1] = (v1 > 0) ? atomicAdd(&wc[(t2 + 1) * 16], v1) : 0;
    int ts = v0 + v1;
    int lane = threadIdx.x & 63;
    int wid = threadIdx.x >> 6;
    int incl = ts;
#pragma unroll
    for (int off = 1; off < 64; off <<= 1) {
        int o = __shfl_up(incl, off);
        if (lane >= off) incl += o;
    }
    if (lane == 63) wsum[wid] = incl;
    __syncthreads();
    if (threadIdx.x == 0) {
        int r = 0;
        for (int i = 0; i < 4; ++i) { wpre[i] = r; r += wsum[i]; }
    }
    __syncthreads();
    int run = wpre[wid] + (incl - ts);
    lsta[t2] = run;
    run += v0;
    lsta[t2 + 1] = run;
    __syncthreads();
    // cursors = starts (reuse lcnt)
    lcnt[t2] = lsta[t2];
    lcnt[t2 + 1] = lsta[t2 + 1];
    __syncthreads();
    // scatter into window-sorted LDS staging
#pragma unroll
    for (int k = 0; k < 16; ++k) {
        int d = d_[k];
        if (d >= 0) {
            int w = ((unsigned)d) >> PWBITS;
            int pos = atomicAdd(&lcnt[w], 1);
            stg[pos] = (((unsigned)(d & (PWIN - 1))) << 18) | (unsigned)s_[k];
            wsl[pos] = (ushort_t)w;
        }
    }
    __syncthreads();
    // coalesced copy-out: consecutive slots in a window run -> consecutive gmem
    int total = E - e0; if (total > PCHUNK) total = PCHUNK;
    for (int slot = threadIdx.x; slot < total; slot += 256) {
        int w = wsl[slot];
        int off = lbase[w] + (slot - lsta[w]);
        if (off < cap) bk[(size_t)w * cap + off] = stg[slot];
    }
}

// ---------------- fill body -------------------------------------------------
__device__ inline void fill_body(
    const unsigned* __restrict__ bk, const int* __restrict__ wc, int cap,
    int* __restrict__ csr, int* __restrict__ cnt, int* __restrict__ rs,
    int N, int w, int* lc, int* wsum, int* wpre)
{
    int d0 = w << PWBITS;
    int sz = wc[w * 16]; if (sz > cap) sz = cap;
    const unsigned* bkt = bk + (size_t)w * cap;
    uint4 u[FW_R];
#pragma unroll
    for (int r = 0; r < FW_R; ++r) {
        int i4 = r * 1024 + threadIdx.x * 4;
        if (i4 + 3 < sz) {
            u[r] = *(const uint4*)(bkt + i4);
        } else {
            u[r].x = (i4 + 0 < sz) ? bkt[i4 + 0] : 0xFFFFFFFFu;
            u[r].y = (i4 + 1 < sz) ? bkt[i4 + 1] : 0xFFFFFFFFu;
            u[r].z = (i4 + 2 < sz) ? bkt[i4 + 2] : 0xFFFFFFFFu;
            u[r].w = (i4 + 3 < sz) ? bkt[i4 + 3] : 0xFFFFFFFFu;
        }
    }
    for (int i = threadIdx.x; i < PWIN; i += 256) lc[i] = 0;
    __syncthreads();
#pragma unroll
    for (int r = 0; r < FW_R; ++r) {
        if (u[r].x != 0xFFFFFFFFu) atomicAdd(&lc[u[r].x >> 18], 1);
        if (u[r].y != 0xFFFFFFFFu) atomicAdd(&lc[u[r].y >> 18], 1);
        if (u[r].z != 0xFFFFFFFFu) atomicAdd(&lc[u[r].z >> 18], 1);
        if (u[r].w != 0xFFFFFFFFu) atomicAdd(&lc[u[r].w >> 18], 1);
    }
    __syncthreads();
    {
        int i = threadIdx.x * 2;
        int d = d0 + i;
        if (d < N)     cnt[d] = lc[i];
        if (d + 1 < N) cnt[d + 1] = lc[i + 1];
    }
    int t2 = threadIdx.x * 2;
    int v0 = lc[t2], v1 = lc[t2 + 1];
    int ts = v0 + v1;
    int lane = threadIdx.x & 63;
    int wid = threadIdx.x >> 6;
    int incl = ts;
#pragma unroll
    for (int off = 1; off < 64; off <<= 1) {
        int o = __shfl_up(incl, off);
        if (lane >= off) incl += o;
    }
    if (lane == 63) wsum[wid] = incl;
    __syncthreads();
    if (threadIdx.x == 0) {
        int r = 0;
        for (int i = 0; i < 4; ++i) { wpre[i] = r; r += wsum[i]; }
    }
    __syncthreads();
    int run = w * cap + wpre[wid] + (incl - ts);
    lc[t2] = run;
    if (d0 + t2 < N) rs[d0 + t2] = run;
    run += v0;
    lc[t2 + 1] = run;
    if (d0 + t2 + 1 < N) rs[d0 + t2 + 1] = run;
    __syncthreads();
#pragma unroll
    for (int r = 0; r < FW_R; ++r) {
        if (u[r].x != 0xFFFFFFFFu) { int p = atomicAdd(&lc[u[r].x >> 18], 1); csr[p] = (int)(u[r].x & 0x3FFFFu); }
        if (u[r].y != 0xFFFFFFFFu) { int p = atomicAdd(&lc[u[r].y >> 18], 1); csr[p] = (int)(u[r].y & 0x3FFFFu); }
        if (u[r].z != 0xFFFFFFFFu) { int p = atomicAdd(&lc[u[r].z >> 18], 1); csr[p] = (int)(u[r].z & 0x3FFFFu); }
        if (u[r].w != 0xFFFFFFFFu) { int p = atomicAdd(&lc[u[r].w >> 18], 1); csr[p] = (int)(u[r].w & 0x3FFFFu); }
    }
}

// ---------------- proj bodies ----------------------------------------------
__device__ inline bf16x8 cvt8(const float* p) {
    float4 a = *(const float4*)p;
    float4 b = *(const float4*)(p + 4);
    bf16x8 r;
    r[0] = (short)f2bf(a.x); r[1] = (short)f2bf(a.y);
    r[2] = (short)f2bf(a.z); r[3] = (short)f2bf(a.w);
    r[4] = (short)f2bf(b.x); r[5] = (short)f2bf(b.y);
    r[6] = (short)f2bf(b.z); r[7] = (short)f2bf(b.w);
    return r;
}

__device__ inline void proj_paper_body(
    int blk, const float* __restrict__ x, const ushort_t* __restrict__ Wfrag,
    const float* __restrict__ bias,
    ushort_t* __restrict__ h_pp, ushort_t* __restrict__ h_pa,
    float* __restrict__ root_p, int N)
{
    int wave = threadIdx.x >> 6, lane = threadIdx.x & 63;
    int mbase = blk * 64 + wave * 16;
    int row = lane & 15, grp = lane >> 4;
    int nA = mbase + row; if (nA > N - 1) nA = N - 1;
    const float* xr = x + (size_t)nA * 64 + grp * 8;
    bf16x8 a0 = cvt8(xr);
    bf16x8 a1 = cvt8(xr + 32);
    f32x4 acc0 = {0.f, 0.f, 0.f, 0.f}, acc1 = acc0, acc2 = acc0, acc3 = acc0;
    float bp0 = bias[row];
    float bp1 = bias[16 + row];
    f32x4 acc4 = {bp0, bp0, bp0, bp0};
    f32x4 acc5 = {bp1, bp1, bp1, bp1};
    const bf16x8* wf = (const bf16x8*)(Wfrag) + lane;
    acc0 = __builtin_amdgcn_mfma_f32_16x16x32_bf16(a0, wf[0 * 64], acc0, 0, 0, 0);
    acc0 = __builtin_amdgcn_mfma_f32_16x16x32_bf16(a1, wf[1 * 64], acc0, 0, 0, 0);
    acc1 = __builtin_amdgcn_mfma_f32_16x16x32_bf16(a0, wf[2 * 64], acc1, 0, 0, 0);
    acc1 = __builtin_amdgcn_mfma_f32_16x16x32_bf16(a1, wf[3 * 64], acc1, 0, 0, 0);
    acc2 = __builtin_amdgcn_mfma_f32_16x16x32_bf16(a0, wf[4 * 64], acc2, 0, 0, 0);
    acc2 = __builtin_amdgcn_mfma_f32_16x16x32_bf16(a1, wf[5 * 64], acc2, 0, 0, 0);
    acc3 = __builtin_amdgcn_mfma_f32_16x16x32_bf16(a0, wf[6 * 64], acc3, 0, 0, 0);
    acc3 = __builtin_amdgcn_mfma_f32_16x16x32_bf16(a1, wf[7 * 64], acc3, 0, 0, 0);
    acc4 = __builtin_amdgcn_mfma_f32_16x16x32_bf16(a0, wf[8 * 64], acc4, 0, 0, 0);
    acc4 = __builtin_amdgcn_mfma_f32_16x16x32_bf16(a1, wf[9 * 64], acc4, 0, 0, 0);
    acc5 = __builtin_amdgcn_mfma_f32_16x16x32_bf16(a0, wf[10 * 64], acc5, 0, 0, 0);
    acc5 = __builtin_amdgcn_mfma_f32_16x16x32_bf16(a1, wf[11 * 64], acc5, 0, 0, 0);
    int node0 = mbase + grp * 4;
#pragma unroll
    for (int reg = 0; reg < 4; ++reg) {
        int nd = node0 + reg;
        if (nd < N) {
            size_t b32 = (size_t)nd * 32;
            h_pp[b32 + row]        = f2bf(acc0[reg]);
            h_pp[b32 + 16 + row]   = f2bf(acc1[reg]);
            h_pa[b32 + row]        = f2bf(acc2[reg]);
            h_pa[b32 + 16 + row]   = f2bf(acc3[reg]);
            root_p[b32 + row]      = acc4[reg];
            root_p[b32 + 16 + row] = acc5[reg];
        }
    }
}

__device__ inline void proj_author_body(
    int blk, const float* __restrict__ x, const ushort_t* __restrict__ Wfrag,
    const float* __restrict__ bias,
    ushort_t* __restrict__ h_ap, float* __restrict__ root_a, int N)
{
    int wave = threadIdx.x >> 6, lane = threadIdx.x & 63;
    int mbase = blk * 64 + wave * 16;
    int row = lane & 15, grp = lane >> 4;
    int nA = mbase + row; if (nA > N - 1) nA = N - 1;
    const float* xr = x + (size_t)nA * 64 + grp * 8;
    bf16x8 a0 = cvt8(xr);
    bf16x8 a1 = cvt8(xr + 32);
    f32x4 acc0 = {0.f, 0.f, 0.f, 0.f}, acc1 = acc0;
    float bp0 = bias[row];
    float bp1 = bias[16 + row];
    f32x4 acc2 = {bp0, bp0, bp0, bp0};
    f32x4 acc3 = {bp1, bp1, bp1, bp1};
    const bf16x8* wf = (const bf16x8*)(Wfrag) + lane;
    acc0 = __builtin_amdgcn_mfma_f32_16x16x32_bf16(a0, wf[0 * 64], acc0, 0, 0, 0);
    acc0 = __builtin_amdgcn_mfma_f32_16x16x32_bf16(a1, wf[1 * 64], acc0, 0, 0, 0);
    acc1 = __builtin_amdgcn_mfma_f32_16x16x32_bf16(a0, wf[2 * 64], acc1, 0, 0, 0);
    acc1 = __builtin_amdgcn_mfma_f32_16x16x32_bf16(a1, wf[3 * 64], acc1, 0, 0, 0);
    acc2 = __builtin_amdgcn_mfma_f32_16x16x32_bf16(a0, wf[4 * 64], acc2, 0, 0, 0);
    acc2 = __builtin_amdgcn_mfma_f32_16x16x32_bf16(a1, wf[5 * 64], acc2, 0, 0, 0);
    acc3 = __builtin_amdgcn_mfma_f32_16x16x32_bf16(a0, wf[6 * 64], acc3, 0, 0, 0);
    acc3 = __builtin_amdgcn_mfma_f32_16x16x32_bf16(a1, wf[7 * 64], acc3, 0, 0, 0);
    int node0 = mbase + grp * 4;
#pragma unroll
    for (int reg = 0; reg < 4; ++reg) {
        int nd = node0 + reg;
        if (nd < N) {
            size_t b32 = (size_t)nd * 32;
            h_ap[b32 + row]        = f2bf(acc0[reg]);
            h_ap[b32 + 16 + row]   = f2bf(acc1[reg]);
            root_a[b32 + row]      = acc2[reg];
            root_a[b32 + 16 + row] = acc3[reg];
        }
    }
}

// fused: fill windows [0, nwt), paper-proj [nwt, nwt+pbp), author after.
__global__ __launch_bounds__(256)
void fill_proj(
    const unsigned* __restrict__ bk0, const int* __restrict__ wc0, int cap0,
    int* __restrict__ csr0, int* __restrict__ cnt0, int* __restrict__ rs0, int N0, int nw0,
    const unsigned* __restrict__ bk1, const int* __restrict__ wc1, int cap1,
    int* __restrict__ csr1, int* __restrict__ cnt1, int* __restrict__ rs1, int N1, int nw1,
    const unsigned* __restrict__ bk2, const int* __restrict__ wc2, int cap2,
    int* __restrict__ csr2, int* __restrict__ cnt2, int* __restrict__ rs2, int N2, int nw2,
    const float* __restrict__ xp, const float* __restrict__ xa,
    const ushort_t* __restrict__ Wfp, const ushort_t* __restrict__ Wfa,
    const float* __restrict__ bias_p, const float* __restrict__ bias_a,
    ushort_t* __restrict__ h_pp, ushort_t* __restrict__ h_pa,
    ushort_t* __restrict__ h_ap,
    float* __restrict__ root_p, float* __restrict__ root_a,
    int NP, int NA, int pbp)
{
    __shared__ int lc[PWIN];
    __shared__ int wsum[4], wpre[4];
    int b = blockIdx.x;
    int nwt = nw0 + nw1 + nw2;
    if (b < nwt) {
        const unsigned* bk; const int* wc; int cap; int* csr; int* cnt; int* rs; int N; int w;
        if (b < nw0)            { bk = bk0; wc = wc0; cap = cap0; csr = csr0; cnt = cnt0; rs = rs0; N = N0; w = b; }
        else if (b < nw0 + nw1) { bk = bk1; wc = wc1; cap = cap1; csr = csr1; cnt = cnt1; rs = rs1; N = N1; w = b - nw0; }
        else                    { bk = bk2; wc = wc2; cap = cap2; csr = csr2; cnt = cnt2; rs = rs2; N = N2; w = b - nw0 - nw1; }
        fill_body(bk, wc, cap, csr, cnt, rs, N, w, lc, wsum, wpre);
    } else if (b < nwt + pbp) {
        proj_paper_body(b - nwt, xp, Wfp, bias_p, h_pp, h_pa, root_p, NP);
    } else {
        proj_author_body(b - nwt - pbp, xa, Wfa, bias_a, h_ap, root_a, NA);
    }
}

#define ACC8(A, U) \
    A[0] += bf2f_lo((U).x); A[1] += bf2f_hi((U).x); \
    A[2] += bf2f_lo((U).y); A[3] += bf2f_hi((U).y); \
    A[4] += bf2f_lo((U).z); A[5] += bf2f_hi((U).z); \
    A[6] += bf2f_lo((U).w); A[7] += bf2f_hi((U).w);

// fused pulls: paper blocks [0, pbp) then author blocks; round-14 bodies.
__global__ __launch_bounds__(256, 8)
void pull_pa(const ushort_t* __restrict__ h_pp, const ushort_t* __restrict__ h_ap,
             const ushort_t* __restrict__ h_pa,
             const float* __restrict__ root_p, const float* __restrict__ root_a,
             const int* __restrict__ csr_pp, const int* __restrict__ rs_pp,
             const int* __restrict__ cnt_pp,
             const int* __restrict__ csr_ap, const int* __restrict__ rs_ap,
             const int* __restrict__ cnt_ap,
             const int* __restrict__ csr_pa, const int* __restrict__ rs_pa,
             const int* __restrict__ cnt_pa,
             const float* __restrict__ vv,
             float* __restrict__ s_pp, float* __restrict__ s_ap,
             float* __restrict__ out, int NP, int NA, int pbp)
{
    __shared__ float v0[32], v1[32];
    __shared__ float c2s;
    int c = threadIdx.x & 3;
    if (blockIdx.x < pbp) {
        if (threadIdx.x < 32) { v0[threadIdx.x] = vv[threadIdx.x]; v1[threadIdx.x] = vv[32 + threadIdx.x]; }
        if (threadIdx.x == 0) c2s = vv[64];
        __syncthreads();
        int n = blockIdx.x * 64 + (threadIdx.x >> 2);
        if (n >= NP) return;
        float a[8];
#pragma unroll
        for (int k = 0; k < 8; ++k) a[k] = 0.f;
        int s1 = rs_pp[n], k1 = cnt_pp[n], e1 = s1 + k1;
        int j = s1;
        for (; j + 4 <= e1; j += 4) {
            int i0 = ntl(csr_pp + j), i1 = ntl(csr_pp + j + 1);
            int i2 = ntl(csr_pp + j + 2), i3 = ntl(csr_pp + j + 3);
            uint4 u0 = ((const uint4*)(h_pp + (size_t)i0 * 32))[c];
            uint4 u1 = ((const uint4*)(h_pp + (size_t)i1 * 32))[c];
            uint4 u2 = ((const uint4*)(h_pp + (size_t)i2 * 32))[c];
            uint4 u3 = ((const uint4*)(h_pp + (size_t)i3 * 32))[c];
            ACC8(a, u0) ACC8(a, u1) ACC8(a, u2) ACC8(a, u3)
        }
        for (; j < e1; ++j) {
            uint4 u0 = ((const uint4*)(h_pp + (size_t)ntl(csr_pp + j) * 32))[c];
            ACC8(a, u0)
        }
        float b8[8];
#pragma unroll
        for (int k = 0; k < 8; ++k) b8[k] = 0.f;
        int s2 = rs_ap[n], k2 = cnt_ap[n], e2 = s2 + k2;
        j = s2;
        for (; j + 4 <= e2; j += 4) {
            int i0 = ntl(csr_ap + j), i1 = ntl(csr_ap + j + 1);
            int i2 = ntl(csr_ap + j + 2), i3 = ntl(csr_ap + j + 3);
            uint4 u0 = ((const uint4*)(h_ap + (size_t)i0 * 32))[c];
            uint4 u1 = ((const uint4*)(h_ap + (size_t)i1 * 32))[c];
            uint4 u2 = ((const uint4*)(h_ap + (size_t)i2 * 32))[c];
            uint4 u3 = ((const uint4*)(h_ap + (size_t)i3 * 32))[c];
            ACC8(b8, u0) ACC8(b8, u1) ACC8(b8, u2) ACC8(b8, u3)
        }
        for (; j < e2; ++j) {
            uint4 u0 = ((const uint4*)(h_ap + (size_t)ntl(csr_ap + j) * 32))[c];
            ACC8(b8, u0)
        }
        float ipp = 1.0f / fmaxf((float)k1, 1.0f);
        float iap = 1.0f / fmaxf((float)k2, 1.0f);
        const float* rt = root_p + (size_t)n * 32 + 8 * c;
        float d0 = 0.f, d1 = 0.f;
#pragma unroll
        for (int k = 0; k < 8; ++k) {
            float p = fmaxf(rt[k] + a[k] * ipp + b8[k] * iap, 0.f);
            d0 += p * v0[8 * c + k];
            d1 += p * v1[8 * c + k];
        }
        d0 += __shfl_xor(d0, 1); d0 += __shfl_xor(d0, 2);
        d1 += __shfl_xor(d1, 1); d1 += __shfl_xor(d1, 2);
        if (c == 0) { s_pp[n] = d0; out[n] = d1 + c2s; }
    } else {
        if (threadIdx.x < 32) v0[threadIdx.x] = vv[96 + threadIdx.x];
        __syncthreads();
        int n = (blockIdx.x - pbp) * 64 + (threadIdx.x >> 2);
        if (n >= NA) return;
        float a[8];
#pragma unroll
        for (int k = 0; k < 8; ++k) a[k] = 0.f;
        int s1 = rs_pa[n], k1 = cnt_pa[n], e1 = s1 + k1;
        int j = s1;
        for (; j + 4 <= e1; j += 4) {
            int i0 = ntl(csr_pa + j), i1 = ntl(csr_pa + j + 1);
            int i2 = ntl(csr_pa + j + 2), i3 = ntl(csr_pa + j + 3);
            uint4 u0 = ((const uint4*)(h_pa + (size_t)i0 * 32))[c];
            uint4 u1 = ((const uint4*)(h_pa + (size_t)i1 * 32))[c];
            uint4 u2 = ((const uint4*)(h_pa + (size_t)i2 * 32))[c];
            uint4 u3 = ((const uint4*)(h_pa + (size_t)i3 * 32))[c];
            ACC8(a, u0) ACC8(a, u1) ACC8(a, u2) ACC8(a, u3)
        }
        for (; j < e1; ++j) {
            uint4 u0 = ((const uint4*)(h_pa + (size_t)ntl(csr_pa + j) * 32))[c];
            ACC8(a, u0)
        }
        float ip = 1.0f / fmaxf((float)k1, 1.0f);
        const float* rt = root_a + (size_t)n * 32 + 8 * c;
        float d0 = 0.f;
#pragma unroll
        for (int k = 0; k < 8; ++k) {
            float p = fmaxf(rt[k] + a[k] * ip, 0.f);
            d0 += p * v0[8 * c + k];
        }
        d0 += __shfl_xor(d0, 1); d0 += __shfl_xor(d0, 2);
        if (c == 0) s_ap[n] = d0;
    }
}

__global__ __launch_bounds__(256, 8)
void pull2(const float* __restrict__ s_pp, const float* __restrict__ s_ap,
           const int* __restrict__ csr_pp, const int* __restrict__ rs_pp,
           const int* __restrict__ cnt_pp,
           const int* __restrict__ csr_ap, const int* __restrict__ rs_ap,
           const int* __restrict__ cnt_ap,
           float* __restrict__ out, int N)
{
    int g = (blockIdx.x * blockDim.x + threadIdx.x) >> 2;
    int c = threadIdx.x & 3;
    if (g >= N) return;
    int s1 = rs_pp[g], k1 = cnt_pp[g], e1 = s1 + k1;
    float t = 0.f;
    for (int j = s1 + c; j < e1; j += 4) t += s_pp[ntl(csr_pp + j)];
    int s2 = rs_ap[g], k2 = cnt_ap[g], e2 = s2 + k2;
    float u = 0.f;
    for (int j = s2 + c; j < e2; j += 4) u += s_ap[ntl(csr_ap + j)];
    t += __shfl_xor(t, 1); t += __shfl_xor(t, 2);
    u += __shfl_xor(u, 1); u += __shfl_xor(u, 2);
    if (c == 0) {
        out[g] += t / fmaxf((float)k1, 1.f) + u / fmaxf((float)k2, 1.f);
    }
}

extern "C" void kernel_launch(void* const* d_in, const int* in_sizes, int n_in,
                              void* d_out, int out_size, void* d_ws, size_t ws_size,
                              hipStream_t stream)
{
    const float* x_paper  = (const float*)d_in[0];
    const float* x_author = (const float*)d_in[1];
    const int* src_pp = (const int*)d_in[2];
    const int* dst_pp = (const int*)d_in[3];
    const int* src_ap = (const int*)d_in[4];
    const int* dst_ap = (const int*)d_in[5];
    const int* src_pa = (const int*)d_in[6];
    const int* dst_pa = (const int*)d_in[7];
    const float* Wl1_pp = (const float*)d_in[8];
    const float* bl1_pp = (const float*)d_in[9];
    const float* Wr1_pp = (const float*)d_in[10];
    const float* Wl1_ap = (const float*)d_in[11];
    const float* bl1_ap = (const float*)d_in[12];
    const float* Wr1_ap = (const float*)d_in[13];
    const float* Wl1_pa = (const float*)d_in[14];
    const float* bl1_pa = (const float*)d_in[15];
    const float* Wr1_pa = (const float*)d_in[16];
    const float* Wl2_pp = (const float*)d_in[17];
    const float* bl2_pp = (const float*)d_in[18];
    const float* Wr2_pp = (const float*)d_in[19];
    const float* Wl2_ap = (const float*)d_in[20];
    const float* bl2_ap = (const float*)d_in[21];
    const float* Wr2_ap = (const float*)d_in[22];
    const float* W_lin  = (const float*)d_in[23];
    const float* b_lin  = (const float*)d_in[24];

    const int NP = in_sizes[0] / 64;
    const int NA = in_sizes[1] / 64;
    const int E_PP = in_sizes[2];
    const int E_AP = in_sizes[4];
    const int E_PA = in_sizes[6];

    const int nw_pp = (NP + PWIN - 1) >> PWBITS;
    const int nw_ap = nw_pp;
    const int nw_pa = (NA + PWIN - 1) >> PWBITS;
    const int cap_pp = ((E_PP / nw_pp + CAPPAD) + 3) & ~3;
    const int cap_ap = ((E_AP / nw_ap + CAPPAD) + 3) & ~3;
    const int cap_pa = ((E_PA / nw_pa + CAPPAD) + 3) & ~3;

    // ---- workspace ----
    char* wp = (char*)d_ws;
    int* wcur = (int*)wp;             wp += (size_t)3 * PWIN * 16 * 4;
    unsigned* bk_pp = (unsigned*)wp;  wp += (size_t)nw_pp * cap_pp * 4;
    unsigned* bk_ap = (unsigned*)wp;  wp += (size_t)nw_ap * cap_ap * 4;
    unsigned* bk_pa = (unsigned*)wp;  wp += (size_t)nw_pa * cap_pa * 4;
    int* csr_pp = (int*)wp;           wp += (size_t)nw_pp * cap_pp * 4;
    int* csr_ap = (int*)wp;           wp += (size_t)nw_ap * cap_ap * 4;
    int* csr_pa = (int*)wp;           wp += (size_t)nw_pa * cap_pa * 4;
    int* cnt    = (int*)wp;           wp += (size_t)(2 * NP + NA) * 4;
    int* rs     = (int*)wp;           wp += (size_t)(2 * NP + NA) * 4;
    ushort_t* h_pp = (ushort_t*)wp;   wp += (size_t)NP * 32 * 2;
    ushort_t* h_pa = (ushort_t*)wp;   wp += (size_t)NP * 32 * 2;
    ushort_t* h_ap = (ushort_t*)wp;   wp += (size_t)NA * 32 * 2;
    float* root_a = (float*)wp;       wp += (size_t)NA * 32 * 4;
    float* s_pp   = (float*)wp;       wp += (size_t)NP * 4;
    float* s_ap   = (float*)wp;       wp += (size_t)NA * 4;
    float* Wcomb_p = (float*)wp;      wp += 64 * 96 * 4;
    float* Wcomb_a = (float*)wp;      wp += 64 * 64 * 4;
    ushort_t* Wfrag_p = (ushort_t*)wp; wp += 12 * 64 * 8 * 2;
    ushort_t* Wfrag_a = (ushort_t*)wp; wp += 8 * 64 * 8 * 2;
    float* bias_p = (float*)wp;       wp += 32 * 4;
    float* bias_a = (float*)wp;       wp += 32 * 4;
    float* vv     = (float*)wp;       wp += 128 * 4;
    size_t used = (size_t)(wp - (char*)d_ws);
    size_t rootp_bytes = (size_t)NP * 32 * 4;
    bool roomy = (used + rootp_bytes) <= ws_size;
    float* root_p = roomy ? (float*)wp : (float*)bk_pp;

    int* cnt_pp = cnt,  * cnt_ap = cnt + NP,  * cnt_pa = cnt + 2 * NP;
    int* rs_pp  = rs,   * rs_ap  = rs + NP,   * rs_pa  = rs + 2 * NP;

    float* out = (float*)d_out;

    hipMemsetAsync(wcur, 0, (size_t)3 * PWIN * 16 * 4, stream);

    prep_weights<<<1, 256, 0, stream>>>(
        Wl1_pp, Wr1_pp, Wl1_ap, Wr1_ap, Wl1_pa, Wr1_pa,
        bl1_pp, bl1_ap, bl1_pa,
        Wl2_pp, bl2_pp, Wr2_pp, Wl2_ap, bl2_ap, Wr2_ap,
        W_lin, b_lin, Wcomb_p, Wcomb_a, Wfrag_p, Wfrag_a, bias_p, bias_a, vv);

    int nb_total = (E_PP + PCHUNK - 1) / PCHUNK + (E_AP + PCHUNK - 1) / PCHUNK
                 + (E_PA + PCHUNK - 1) / PCHUNK;
    int pbp = (NP + 63) / 64;
    int pba = (NA + 63) / 64;
    int nwt = nw_pp + nw_ap + nw_pa;

    partition3<<<nb_total, 256, 0, stream>>>(
        src_pp, dst_pp, E_PP, bk_pp, cap_pp, nw_pp, wcur + 0,
        src_ap, dst_ap, E_AP, bk_ap, cap_ap, nw_ap, wcur + PWIN * 16,
        src_pa, dst_pa, E_PA, bk_pa, cap_pa, nw_pa, wcur + 2 * PWIN * 16);

    if (roomy) {
        fill_proj<<<nwt + pbp + pba, 256, 0, stream>>>(
            bk_pp, wcur + 0,             cap_pp, csr_pp, cnt_pp, rs_pp, NP, nw_pp,
            bk_ap, wcur + PWIN * 16,     cap_ap, csr_ap, cnt_ap, rs_ap, NP, nw_ap,
            bk_pa, wcur + 2 * PWIN * 16, cap_pa, csr_pa, cnt_pa, rs_pa, NA, nw_pa,
            x_paper, x_author, Wfrag_p, Wfrag_a, bias_p, bias_a,
            h_pp, h_pa, h_ap, root_p, root_a, NP, NA, pbp);
    } else {
        fill_proj<<<nwt, 256, 0, stream>>>(
            bk_pp, wcur + 0,             cap_pp, csr_pp, cnt_pp, rs_pp, NP, nw_pp,
            bk_ap, wcur + PWIN * 16,     cap_ap, csr_ap, cnt_ap, rs_ap, NP, nw_ap,
            bk_pa, wcur + 2 * PWIN * 16, cap_pa, csr_pa, cnt_pa, rs_pa, NA, nw_pa,
            x_paper, x_author, Wfrag_p, Wfrag_a, bias_p, bias_a,
            h_pp, h_pa, h_ap, root_p, root_a, NP, NA, 0x40000000);
        fill_proj<<<pbp + pba, 256, 0, stream>>>(
            bk_pp, wcur + 0,             cap_pp, csr_pp, cnt_pp, rs_pp, NP, 0,
            bk_ap, wcur + PWIN * 16,     cap_ap, csr_ap, cnt_ap, rs_ap, NP, 0,
            bk_pa, wcur + 2 * PWIN * 16, cap_pa, csr_pa, cnt_pa, rs_pa, NA, 0,
            x_paper, x_author, Wfrag_p, Wfrag_a, bias_p, bias_a,
            h_pp, h_pa, h_ap, root_p, root_a, NP, NA, pbp);
    }

    pull_pa<<<pbp + pba, 256, 0, stream>>>(
        h_pp, h_ap, h_pa, root_p, root_a,
        csr_pp, rs_pp, cnt_pp, csr_ap, rs_ap, cnt_ap, csr_pa, rs_pa, cnt_pa,
        vv, s_pp, s_ap, out, NP, NA, pbp);

    pull2<<<((size_t)NP * 4 + 255) / 256, 256, 0, stream>>>(
        s_pp, s_ap, csr_pp, rs_pp, cnt_pp, csr_ap, rs_ap, cnt_ap, out, NP);
}